// Round 8
// baseline (198.935 us; speedup 1.0000x reference)
//
#include <hip/hip_runtime.h>

// MSE_DQ_FK: dual-quaternion denorm -> local rot -> FK -> mse losses -> scalar.
// B=64, T=1024, J=22, C=176. Layout (B,C,T), T contiguous. Only rotation
// quats (4 of 8 dq channels) are read. Telescoping identity: global rot[j] =
// conj(q0n)*qjn; ik/dec roots are identity.
//
// Round-10 structure: ASYNC global_load_lds STAGING (m201 pattern).
//   Cross-round cycle accounting: R5/R6 = ~170 vmem loads/wave at 1
//   wave/SIMD in 45.5us = ~640 cy per load instr -> FULL latency, zero MLP.
//   Register-prefetch MLP is structurally capped: scheduler sinks loads to
//   uses under pressure (R6 = R5 exactly), fencing them spills (R7:
//   WRITE_SIZE 1.3->30MB, 61us), and TLP is capped by total threads
//   (65536 poses / pose-pair = 4 waves/CU).
//   Fix: stage via __builtin_amdgcn_global_load_lds -- fire-and-forget DMA,
//   vmcnt-tracked, ZERO destination VGPRs -> deep MLP without spill.
//   Compute reads LDS (ds_read_b64, ~6-12cy) instead of global (~640cy).
//   Per block (256 thr = 4 waves, 512 poses, one role):
//     chunk = 2 joints x 2 streams x 4 ch x 512 poses x 4B = 32KB
//     double buffer = 64KB LDS; 32 DMA instrs/chunk = 8 per wave
//     pipeline: stage k+1 -> vmcnt(8) [k done, k+1 in flight] ->
//               RAW s_barrier (NOT __syncthreads: that drains vmcnt(0)) ->
//               compute k from LDS -> barrier -> ...
//   Chunks: [1,2][3,4][5,6][7,8][9,10][11,12][13,14][15,16][17,18][19,20][21]
//     role 0 (blocks 0-127):   {ik, tgt} -> EE losses (joints 4,8,13,17,21)
//     role 1 (blocks 128-255): {dec, ik} -> REG losses (16 non-sparse)
//   HBM floor ~67MB unique / 6.3TB/s ~= 10.6us.
//  * UNIT-QUAT FROBENIUS IDENTITY: ||R(a)-R(b)||_F^2 = 8*(1 - dot(a,b)^2).

#define T_DIM 1024
#define SB() __builtin_amdgcn_sched_barrier(0)

// counted-vmcnt gate: chunk ready for all waves. SB pins DMA issues above
// the wait and the wait above the ds_reads (rule-18 analog).
#define GATE(N) do { SB(); \
    asm volatile("s_waitcnt vmcnt(" #N ")" ::: "memory"); SB(); \
    __builtin_amdgcn_s_barrier(); } while (0)
// end-of-compute barrier: all waves done reading buf before it is re-staged
#define ENDB() do { SB(); __builtin_amdgcn_s_barrier(); } while (0)

typedef __attribute__((address_space(1))) const float glb_cf;
typedef __attribute__((address_space(3))) float lds_f;

// async 16B/lane global->LDS DMA. LDS dest = wave-uniform base + lane*16.
__device__ __forceinline__ void dma16(const float* g, float* l) {
    __builtin_amdgcn_global_load_lds((glb_cf*)g, (lds_f*)l, 16, 0, 0);
}

struct alignas(8) F2 { float u, v; };

__device__ __forceinline__ F2 operator+(F2 a, F2 b){ return {a.u+b.u, a.v+b.v}; }
__device__ __forceinline__ F2 operator-(F2 a, F2 b){ return {a.u-b.u, a.v-b.v}; }
__device__ __forceinline__ F2 operator*(F2 a, F2 b){ return {a.u*b.u, a.v*b.v}; }
__device__ __forceinline__ F2 operator*(F2 a, float s){ return {a.u*s, a.v*s}; }
__device__ __forceinline__ F2 operator+(F2 a, float s){ return {a.u+s, a.v+s}; }
__device__ __forceinline__ F2 f2neg(F2 a){ return {-a.u, -a.v}; }
__device__ __forceinline__ F2 f2bc(float s){ return {s, s}; }
__device__ __forceinline__ F2 f2rsq(F2 a){ return {rsqrtf(a.u), rsqrtf(a.v)}; }

struct Q2 { F2 w, x, y, z; };
struct V2 { F2 x, y, z; };
struct St2 { Q2 rot; V2 pos; };

__device__ __forceinline__ Q2 qmul2(const Q2 a, const Q2 b) {
    Q2 r;
    r.w = a.w*b.w - a.x*b.x - a.y*b.y - a.z*b.z;
    r.x = a.w*b.x + a.x*b.w + a.y*b.z - a.z*b.y;
    r.y = a.w*b.y - a.x*b.z + a.y*b.w + a.z*b.x;
    r.z = a.w*b.z + a.x*b.y - a.y*b.x + a.z*b.w;
    return r;
}

__device__ __forceinline__ V2 qrot2(const Q2 q, float ox, float oy, float oz) {
    F2 tx = (q.y*oz - q.z*oy)*2.f;
    F2 ty = (q.z*ox - q.x*oz)*2.f;
    F2 tz = (q.x*oy - q.y*ox)*2.f;
    V2 r;
    r.x = (q.w*tx + (q.y*tz - q.z*ty)) + ox;
    r.y = (q.w*ty + (q.z*tx - q.x*tz)) + oy;
    r.z = (q.w*tz + (q.x*ty - q.y*tx)) + oz;
    return r;
}

// ||R(a)-R(b)||_F^2 for UNIT quats = 8*(1 - dot(a,b)^2)
__device__ __forceinline__ F2 rmdiff2u(const Q2 a, const Q2 b) {
    F2 d = a.w*b.w + a.x*b.x + a.y*b.y + a.z*b.z;
    return (f2bc(1.f) - d*d)*8.f;
}

__device__ __forceinline__ F2 pdiff2(const V2 a, const V2 b) {
    F2 dx = a.x-b.x, dy = a.y-b.y, dz = a.z-b.z;
    return dx*dx + dy*dy + dz*dz;
}

__device__ __forceinline__ Q2 mkq2(const F2 r[4], const int c0,
                                   const float* __restrict__ mean,
                                   const float* __restrict__ stdv) {
    Q2 q;
    q.w = r[0]*stdv[c0+0] + mean[c0+0];
    q.x = r[1]*stdv[c0+1] + mean[c0+1];
    q.y = r[2]*stdv[c0+2] + mean[c0+2];
    q.z = r[3]*stdv[c0+3] + mean[c0+3];
    F2 inv = f2rsq(q.w*q.w + q.x*q.x + q.y*q.y + q.z*q.z);
    q.w = q.w*inv; q.x = q.x*inv; q.y = q.y*inv; q.z = q.z*inv;
    return q;
}

// Stage joints J0..J0+NJ-1 (both streams, 4 quat ch, 512 poses) into lbuf.
// LDS row layout: r = jj*8 + s*4 + ch, 512 floats (2KB) per row; each row
// is 2 DMA slots (2 halves x 256 floats = 1KB = 64 lanes x 16B).
// slot k: r=k>>1, h=k&1. Wave w issues slots [w*per, w*per+per).
// ik base pre-shifted by -8*T_DIM (its array lacks the root joint).
template<int J0, int NJ>
__device__ __forceinline__ void stage(
    const float* __restrict__ xp, const float* __restrict__ yp,
    float* __restrict__ lbuf, const int tblk, const int w, const int lane)
{
    constexpr int per = NJ*16/4;   // DMA instrs per wave: 8 (NJ=2) / 4 (NJ=1)
#pragma unroll
    for (int q = 0; q < per; ++q) {
        const int k  = w*per + q;
        const int r  = k >> 1;
        const int h  = k & 1;
        const int jj = r >> 3;
        const int s  = (r >> 2) & 1;
        const int ch = r & 3;
        const float* sb = s ? yp : xp;
        const float* g = sb + ((J0+jj)*8 + ch)*T_DIM + tblk + h*256 + lane*4;
        float* l = lbuf + r*512 + h*256;   // lane*16B appended by HW
        dma16(g, l);
    }
}

// One joint step; raw quat channels read from LDS (ds_read_b64 pairs).
template<int J, bool LOSS, bool PRE>
__device__ __forceinline__ void stepl(
    St2& sx, St2& sy, const float* __restrict__ lds, const int t0,
    const float* __restrict__ mean, const float* __restrict__ stdv,
    const float* __restrict__ offs, const Q2& q0c, F2& ap, F2& ar)
{
    constexpr int c  = (J-1) >> 1;               // chunk
    constexpr int jj = (J-1) & 1;                // joint-in-chunk
    constexpr int fb = (c & 1)*8192 + jj*8*512;  // float base in LDS
    F2 xr[4], yr[4];
#pragma unroll
    for (int ch = 0; ch < 4; ++ch) {
        xr[ch] = *reinterpret_cast<const F2*>(lds + fb + ch*512 + t0);
        yr[ch] = *reinterpret_cast<const F2*>(lds + fb + (4+ch)*512 + t0);
    }
    const int c0 = J*8;
    Q2 qx = mkq2(xr, c0, mean, stdv);
    Q2 qy = mkq2(yr, c0, mean, stdv);
    if (PRE) qy = qmul2(q0c, qy);
    const float ox = offs[3*J], oy = offs[3*J+1], oz = offs[3*J+2];
    V2 dx = qrot2(sx.rot, ox, oy, oz);
    V2 dy = qrot2(sy.rot, ox, oy, oz);
    V2 px = { dx.x + sx.pos.x, dx.y + sx.pos.y, dx.z + sx.pos.z };
    V2 py = { dy.x + sy.pos.x, dy.y + sy.pos.y, dy.z + sy.pos.z };
    if (LOSS) {
        ap = ap + pdiff2(px, py);
        ar = ar + rmdiff2u(qx, qy);
    }
    sx.rot = qx; sx.pos = px;
    sy.rot = qy; sy.pos = py;
}

// EE joints (chain ends): 4, 8, 13, 17, 21
constexpr bool kEE[22] = {false,false,false,false,true,  false,false,false,true,
                          false,false,false,false,true,  false,false,false,true,
                          false,false,false,true};

#define STEPJ(J) stepl<J, (EEROLE ? kEE[J] : !kEE[J]), EEROLE>( \
                     sx, sy, lds, t0, mean, stdv, offs, q0c, ap, ar)

// PARENTS = [0,0,1,2,3, 0,5,6,7, 0,9,10,11,12, 11,14,15,16, 11,18,19,20]
// Chains: A=1..4  B=5..8  C=9..13 (branch@11)  D=14..17  E=18..21
template<bool EEROLE>
__device__ __forceinline__ void walkL(
    const float* __restrict__ xp, const float* __restrict__ yp,
    float* __restrict__ lds, const int tblk, const int t0,
    const int w, const int lane,
    const float* __restrict__ mean, const float* __restrict__ stdv,
    const float* __restrict__ offs, F2& ap, F2& ar)
{
    float* b0 = lds;
    float* b1 = lds + 8192;

    // root quat (EE role only): 4 plain loads, oldest in the vmem queue ->
    // retired by the first GATE(8) together with chunk 0.
    F2 rq0[4];
    if (EEROLE) {
#pragma unroll
        for (int c2 = 0; c2 < 4; ++c2)
            rq0[c2] = *reinterpret_cast<const F2*>(yp + c2*T_DIM + tblk + t0);
    }

    stage<1,2>(xp, yp, b0, tblk, w, lane);   // c0: j1,j2
    stage<3,2>(xp, yp, b1, tblk, w, lane);   // c1: j3,j4
    GATE(8);                                 // c0 ready (c1 in flight)

    Q2 q0c = { f2bc(1.f), f2bc(0.f), f2bc(0.f), f2bc(0.f) };
    if (EEROLE) {
        Q2 q0 = mkq2(rq0, 0, mean, stdv);
        q0c = { q0.w, f2neg(q0.x), f2neg(q0.y), f2neg(q0.z) };
    }
    const St2 root = { { f2bc(1.f), f2bc(0.f), f2bc(0.f), f2bc(0.f) },
                       { f2bc(0.f), f2bc(0.f), f2bc(0.f) } };
    St2 sx = root, sy = root;
    St2 sx11, sy11;

    STEPJ(1); STEPJ(2);                      // c0 (chain A interior)
    ENDB();
    stage<5,2>(xp, yp, b0, tblk, w, lane);   // c2: j5,j6
    GATE(8);                                 // c1 ready
    STEPJ(3); STEPJ(4);                      // c1 (j4 = EE of A)
    ENDB();
    stage<7,2>(xp, yp, b1, tblk, w, lane);   // c3: j7,j8
    GATE(8);                                 // c2 ready
    sx = root; sy = root;                    // chain B starts
    STEPJ(5); STEPJ(6);
    ENDB();
    stage<9,2>(xp, yp, b0, tblk, w, lane);   // c4: j9,j10
    GATE(8);                                 // c3 ready
    STEPJ(7); STEPJ(8);                      // j8 = EE of B
    ENDB();
    stage<11,2>(xp, yp, b1, tblk, w, lane);  // c5: j11,j12
    GATE(8);                                 // c4 ready
    sx = root; sy = root;                    // chain C starts
    STEPJ(9); STEPJ(10);
    ENDB();
    stage<13,2>(xp, yp, b0, tblk, w, lane);  // c6: j13,j14
    GATE(8);                                 // c5 ready
    STEPJ(11);                               // branch point
    sx11 = sx; sy11 = sy;
    STEPJ(12);
    ENDB();
    stage<15,2>(xp, yp, b1, tblk, w, lane);  // c7: j15,j16
    GATE(8);                                 // c6 ready
    STEPJ(13);                               // EE of C
    sx = sx11; sy = sy11;                    // chain D from branch
    STEPJ(14);
    ENDB();
    stage<17,2>(xp, yp, b0, tblk, w, lane);  // c8: j17,j18
    GATE(8);                                 // c7 ready
    STEPJ(15); STEPJ(16);
    ENDB();
    stage<19,2>(xp, yp, b1, tblk, w, lane);  // c9: j19,j20
    GATE(8);                                 // c8 ready
    STEPJ(17);                               // EE of D
    sx = sx11; sy = sy11;                    // chain E from branch
    STEPJ(18);
    ENDB();
    stage<21,1>(xp, yp, b0, tblk, w, lane);  // c10: j21 (4 instrs/wave)
    GATE(4);                                 // c9 ready (c10's 4 in flight)
    STEPJ(19); STEPJ(20);
    ENDB();
    GATE(0);                                 // c10 ready
    STEPJ(21);                               // EE of E
}

__global__ __launch_bounds__(256) void fk_loss_kernel(
    const float* __restrict__ ik, const float* __restrict__ dec,
    const float* __restrict__ tgt, const float* __restrict__ mean,
    const float* __restrict__ stdv, const float* __restrict__ offs,
    float* __restrict__ out)
{
    extern __shared__ float lds[];   // 2 x 8192 floats = 64 KB (dynamic)
    const int tid = threadIdx.x;
    const int bid = blockIdx.x;
    // 128 pose-blocks x 2 roles = 256 blocks. bid and bid+128 are congruent
    // mod 8 -> same XCD -> role 1's ik re-read hits that XCD's L2.
    const int role = bid >> 7;
    const int pb   = bid & 127;          // pose block: 512 poses
    const int bb   = pb >> 1;            // batch index b (block-uniform)
    const int tblk = (pb & 1) * 512;     // t-range base within batch row
    const int t0   = 2 * tid;            // local pose pair (even, [0,512))
    const int w    = tid >> 6;
    const int lane = tid & 63;

    // ik base pre-shifted by -8*T_DIM (array lacks root joint; j>=1 always).
    const float* ikp = ik  + (size_t)bb * (168*1024) - (size_t)(8*T_DIM);
    const float* dep = dec + (size_t)bb * (176*1024);
    const float* tgp = tgt + (size_t)bb * (176*1024);

    F2 ap = f2bc(0.f), ar = f2bc(0.f);
    float loss;
    const float BT = 65536.f;
    if (role == 0) {
        // loss_ee = ee_pos/(B*T*5*3) + ee_rm/(B*T*5*9)
        walkL<true>(ikp, tgp, lds, tblk, t0, w, lane, mean, stdv, offs, ap, ar);
        loss = (ap.u + ap.v) * (1.0f/(BT*15.f))
             + (ar.u + ar.v) * (1.0f/(BT*45.f));
    } else {
        // loss_reg = 0.1*( reg_pos/(B*T*16*3) + reg_rm/(B*T*16*9) )
        walkL<false>(dep, ikp, lds, tblk, t0, w, lane, mean, stdv, offs, ap, ar);
        loss = (ap.u + ap.v) * (0.1f/(BT*48.f))
             + (ar.u + ar.v) * (0.1f/(BT*144.f));
    }

    // wave(64) shuffle reduce -> cross-wave via spare LDS -> 1 atomic/block.
    // b0 rows 8..15 (floats [4096,8192)) are untouched by chunk 10.
#pragma unroll
    for (int o = 32; o > 0; o >>= 1) loss += __shfl_down(loss, o);
    float* swred = lds + 4096;
    if ((tid & 63) == 0) swred[tid >> 6] = loss;
    __syncthreads();                 // full drain is fine at the end
    if (tid == 0) {
        atomicAdd(out, swred[0]+swred[1]+swred[2]+swred[3]);
    }
}

extern "C" void kernel_launch(void* const* d_in, const int* in_sizes, int n_in,
                              void* d_out, int out_size, void* d_ws, size_t ws_size,
                              hipStream_t stream) {
    // inputs (setup_inputs order): input(unused), input_ik, input_decoder,
    // target, mean_dqs, std_dqs, offsets
    const float* ikx  = (const float*)d_in[1];
    const float* dec  = (const float*)d_in[2];
    const float* tgt  = (const float*)d_in[3];
    const float* mean = (const float*)d_in[4];
    const float* stdv = (const float*)d_in[5];
    const float* offs = (const float*)d_in[6];
    float* out = (float*)d_out;

    hipMemsetAsync(out, 0, sizeof(float), stream);
    // 128 pose-blocks x 2 roles = 256 blocks x 256 threads, 64KB dynamic LDS
    // (1 block/CU); async DMA double-buffer hides global latency.
    fk_loss_kernel<<<256, 256, 65536, stream>>>(ikx, dec, tgt, mean, stdv, offs, out);
}